// Round 2
// baseline (389.969 us; speedup 1.0000x reference)
//
#include <hip/hip_runtime.h>

#define B_   32
#define HW_  3136
#define C_   512
#define H_   128

// ---------------------------------------------------------------------------
// Kernel 1: per-(batch, chunk) column sums of (c + w + h).
// Grid: dim3(CH, B_), 256 threads. Threads = 2 rows x 128 float4-columns.
// Each iteration consumes 2 consecutive rows (fully coalesced 4 KB/array).
// In-block LDS reduction folds the 2-row split -> one partial row per block.
// ---------------------------------------------------------------------------
__global__ __launch_bounds__(256) void ps_kernel(
    const float4* __restrict__ c4,
    const float4* __restrict__ w4,
    const float4* __restrict__ h4,
    float4* __restrict__ partial,
    int rows)                               // rows per chunk (HW_ / CH)
{
    const int k    = blockIdx.x;            // chunk
    const int b    = blockIdx.y;            // batch
    const int CH   = gridDim.x;
    const int col4 = threadIdx.x & 127;     // float4 column (128 * 4 = 512)
    const int rl   = threadIdx.x >> 7;      // row-local 0/1

    long base = ((long)b * HW_ + (long)k * rows + rl) * (C_ / 4) + col4;
    float4 acc = make_float4(0.f, 0.f, 0.f, 0.f);

    #pragma unroll 4
    for (int r = 0; r < rows; r += 2) {
        const float4 a = c4[base];
        const float4 v = w4[base];
        const float4 u = h4[base];
        acc.x += a.x + v.x + u.x;
        acc.y += a.y + v.y + u.y;
        acc.z += a.z + v.z + u.z;
        acc.w += a.w + v.w + u.w;
        base += 2 * (C_ / 4);
    }

    __shared__ float4 red[128];
    if (rl == 1) red[col4] = acc;
    __syncthreads();
    if (rl == 0) {
        const float4 o = red[col4];
        acc.x += o.x; acc.y += o.y; acc.z += o.z; acc.w += o.w;
        partial[((long)b * CH + k) * (C_ / 4) + col4] = acc;
    }
}

// ---------------------------------------------------------------------------
// Kernel 2: reduce partials -> mean s (B,C); fc1 + tanh-GELU; fc2 + bias;
// 3-way softmax -> wbuf (B, 3*C). One block per batch, 256 threads.
// ---------------------------------------------------------------------------
__global__ __launch_bounds__(256) void mlp_kernel(
    const float* __restrict__ partial,
    const float* __restrict__ fc1_w,
    const float* __restrict__ fc1_b,
    const float* __restrict__ fc2_w,
    const float* __restrict__ fc2_b,
    float* __restrict__ wbuf,
    int CH)
{
    __shared__ float s_lds[C_];
    __shared__ float y_lds[H_];

    const int b = blockIdx.x;
    const int t = threadIdx.x;

    // mean over HW (sum of CH partials)
    for (int c = t; c < C_; c += 256) {
        float acc = 0.f;
        const float* __restrict__ p = partial + (long)b * CH * C_ + c;
        for (int k = 0; k < CH; ++k) acc += p[(long)k * C_];
        s_lds[c] = acc * (1.0f / (float)HW_);
    }
    __syncthreads();

    // fc1 + GELU(tanh approx)
    if (t < H_) {
        float acc = fc1_b[t];
        const float* __restrict__ wr = fc1_w + (long)t * C_;
        #pragma unroll 8
        for (int c = 0; c < C_; ++c) acc += s_lds[c] * wr[c];
        const float x = acc;
        const float u = 0.7978845608028654f * (x + 0.044715f * x * x * x);
        y_lds[t] = 0.5f * x * (1.0f + tanhf(u));
    }
    __syncthreads();

    // fc2 + softmax over the 3 branches
    for (int c = t; c < C_; c += 256) {
        float lg[3];
        #pragma unroll
        for (int j = 0; j < 3; ++j) {
            const int row = j * C_ + c;
            float acc = fc2_b[row];
            const float* __restrict__ wr = fc2_w + (long)row * H_;
            #pragma unroll 8
            for (int h = 0; h < H_; ++h) acc += y_lds[h] * wr[h];
            lg[j] = acc;
        }
        const float m  = fmaxf(lg[0], fmaxf(lg[1], lg[2]));
        const float e0 = __expf(lg[0] - m);
        const float e1 = __expf(lg[1] - m);
        const float e2 = __expf(lg[2] - m);
        const float inv = 1.0f / (e0 + e1 + e2);
        float* __restrict__ wb = wbuf + (long)b * 3 * C_;
        wb[0 * C_ + c] = e0 * inv;
        wb[1 * C_ + c] = e1 * inv;
        wb[2 * C_ + c] = e2 * inv;
    }
}

// ---------------------------------------------------------------------------
// Kernel 3: out = c*w0 + w*w1 + h*w2. Grid: dim3(98, B_), 256 threads.
// Block offsets step by 256 float4 (multiple of 128) -> each thread's column
// (and hence its 3 weight float4s) is loop-invariant: hoisted out of the loop.
// ---------------------------------------------------------------------------
__global__ __launch_bounds__(256) void out_kernel(
    const float4* __restrict__ c4,
    const float4* __restrict__ w4,
    const float4* __restrict__ h4,
    const float4* __restrict__ wb4,
    float4* __restrict__ o4)
{
    const int blk  = blockIdx.x;            // 0..97
    const int b    = blockIdx.y;            // batch
    const int t    = threadIdx.x;
    const int col4 = t & 127;

    const float4* __restrict__ wb = wb4 + (long)b * (3 * C_ / 4);
    const float4 w0 = wb[col4];
    const float4 w1 = wb[128 + col4];
    const float4 w2 = wb[256 + col4];

    // per-batch float4 count = HW_ * C_/4 = 401408 = 98 blocks * 16 iters * 256
    long idx = (long)b * (HW_ * (C_ / 4)) + (long)blk * 4096 + t;
    #pragma unroll 4
    for (int it = 0; it < 16; ++it) {
        const float4 a = c4[idx];
        const float4 v = w4[idx];
        const float4 u = h4[idx];
        float4 o;
        o.x = a.x * w0.x + v.x * w1.x + u.x * w2.x;
        o.y = a.y * w0.y + v.y * w1.y + u.y * w2.y;
        o.z = a.z * w0.z + v.z * w1.z + u.z * w2.z;
        o.w = a.w * w0.w + v.w * w1.w + u.w * w2.w;
        o4[idx] = o;
        idx += 256;
    }
}

// ---------------------------------------------------------------------------
extern "C" void kernel_launch(void* const* d_in, const int* in_sizes, int n_in,
                              void* d_out, int out_size, void* d_ws, size_t ws_size,
                              hipStream_t stream)
{
    const float* c_e   = (const float*)d_in[0];
    const float* w_e   = (const float*)d_in[1];
    const float* h_e   = (const float*)d_in[2];
    const float* fc1_w = (const float*)d_in[3];
    const float* fc1_b = (const float*)d_in[4];
    const float* fc2_w = (const float*)d_in[5];
    const float* fc2_b = (const float*)d_in[6];
    float* out = (float*)d_out;

    // choose chunks/batch from available workspace (partial + wbuf, floats)
    int CH = 98;
    {
        const size_t need98 = ((size_t)B_ * 98 * C_ + (size_t)B_ * 3 * C_) * 4;
        const size_t need49 = ((size_t)B_ * 49 * C_ + (size_t)B_ * 3 * C_) * 4;
        if (ws_size < need98) CH = 49;
        if (ws_size < need49) CH = 32;
    }
    const int rows = HW_ / CH;   // 32 / 64 / 98 (all even)

    float* partial = (float*)d_ws;
    float* wbuf    = partial + (long)B_ * CH * C_;

    ps_kernel<<<dim3(CH, B_), 256, 0, stream>>>(
        (const float4*)c_e, (const float4*)w_e, (const float4*)h_e,
        (float4*)partial, rows);
    mlp_kernel<<<B_, 256, 0, stream>>>(partial, fc1_w, fc1_b, fc2_w, fc2_b, wbuf, CH);
    out_kernel<<<dim3(98, B_), 256, 0, stream>>>(
        (const float4*)c_e, (const float4*)w_e, (const float4*)h_e,
        (const float4*)wbuf, (float4*)out);
}

// Round 3
// 330.401 us; speedup vs baseline: 1.1803x; 1.1803x over previous
//
#include <hip/hip_runtime.h>

#define B_   32
#define HW_  3136
#define C_   512
#define H_   128
#define CH_  49                         // partial chunks per batch
#define BPB_ (HW_ * (C_ / 4))           // float4 per batch = 401408

// ---------------------------------------------------------------------------
// Kernel 1: per-batch column partial sums of (c + w + h), strided-within-batch.
// Grid: dim3(CH_, B_) = 1568 blocks (all co-resident). Each block strides by
// CH_*256 float4 through its batch's 401408-float4 span -> active reads cover
// the whole address range at all times (the pattern that measured 5.7 TB/s).
// col4 = t&127 is loop-invariant (stride % 128 == 0), so each thread
// accumulates one float4 column; LDS folds the two row-halves.
// ---------------------------------------------------------------------------
__global__ __launch_bounds__(256) void ps_kernel(
    const float4* __restrict__ c4,
    const float4* __restrict__ w4,
    const float4* __restrict__ h4,
    float4* __restrict__ partial)
{
    const int bx   = blockIdx.x;        // 0..CH_-1
    const int b    = blockIdx.y;        // batch
    const int t    = threadIdx.x;
    const int col4 = t & 127;
    const int rl   = t >> 7;

    const int STRIDE = CH_ * 256;       // 12544 float4
    long idx = (long)b * BPB_ + bx * 256 + t;

    float4 acc = make_float4(0.f, 0.f, 0.f, 0.f);

    // 32 iterations; software-pipeline one deep for load ILP
    float4 a0 = c4[idx], v0 = w4[idx], u0 = h4[idx];
    #pragma unroll 4
    for (int it = 1; it < 32; ++it) {
        const long nidx = idx + STRIDE;
        const float4 a1 = c4[nidx];
        const float4 v1 = w4[nidx];
        const float4 u1 = h4[nidx];
        acc.x += a0.x + v0.x + u0.x;
        acc.y += a0.y + v0.y + u0.y;
        acc.z += a0.z + v0.z + u0.z;
        acc.w += a0.w + v0.w + u0.w;
        a0 = a1; v0 = v1; u0 = u1;
        idx = nidx;
    }
    acc.x += a0.x + v0.x + u0.x;
    acc.y += a0.y + v0.y + u0.y;
    acc.z += a0.z + v0.z + u0.z;
    acc.w += a0.w + v0.w + u0.w;

    __shared__ float4 red[128];
    if (rl == 1) red[col4] = acc;
    __syncthreads();
    if (rl == 0) {
        const float4 o = red[col4];
        acc.x += o.x; acc.y += o.y; acc.z += o.z; acc.w += o.w;
        partial[((long)b * CH_ + bx) * (C_ / 4) + col4] = acc;
    }
}

// ---------------------------------------------------------------------------
// Kernel 2: reduce partials -> mean s (B,C); fc1 + tanh-GELU; fc2 + bias;
// 3-way softmax -> wbuf (B, 3*C). One block per batch, 256 threads.
// ---------------------------------------------------------------------------
__global__ __launch_bounds__(256) void mlp_kernel(
    const float* __restrict__ partial,
    const float* __restrict__ fc1_w,
    const float* __restrict__ fc1_b,
    const float* __restrict__ fc2_w,
    const float* __restrict__ fc2_b,
    float* __restrict__ wbuf)
{
    __shared__ float s_lds[C_];
    __shared__ float y_lds[H_];

    const int b = blockIdx.x;
    const int t = threadIdx.x;

    for (int c = t; c < C_; c += 256) {
        float acc = 0.f;
        const float* __restrict__ p = partial + (long)b * CH_ * C_ + c;
        #pragma unroll
        for (int k = 0; k < CH_; ++k) acc += p[(long)k * C_];
        s_lds[c] = acc * (1.0f / (float)HW_);
    }
    __syncthreads();

    if (t < H_) {
        float acc = fc1_b[t];
        const float* __restrict__ wr = fc1_w + (long)t * C_;
        #pragma unroll 8
        for (int c = 0; c < C_; ++c) acc += s_lds[c] * wr[c];
        const float x = acc;
        const float u = 0.7978845608028654f * (x + 0.044715f * x * x * x);
        y_lds[t] = 0.5f * x * (1.0f + tanhf(u));
    }
    __syncthreads();

    for (int c = t; c < C_; c += 256) {
        float lg[3];
        #pragma unroll
        for (int j = 0; j < 3; ++j) {
            const int row = j * C_ + c;
            float acc = fc2_b[row];
            const float* __restrict__ wr = fc2_w + (long)row * H_;
            #pragma unroll 8
            for (int h = 0; h < H_; ++h) acc += y_lds[h] * wr[h];
            lg[j] = acc;
        }
        const float m  = fmaxf(lg[0], fmaxf(lg[1], lg[2]));
        const float e0 = __expf(lg[0] - m);
        const float e1 = __expf(lg[1] - m);
        const float e2 = __expf(lg[2] - m);
        const float inv = 1.0f / (e0 + e1 + e2);
        float* __restrict__ wb = wbuf + (long)b * 3 * C_;
        wb[0 * C_ + c] = e0 * inv;
        wb[1 * C_ + c] = e1 * inv;
        wb[2 * C_ + c] = e2 * inv;
    }
}

// ---------------------------------------------------------------------------
// Kernel 3: out = c*w0 + w*w1 + h*w2. Flat grid-stride (the R0 form that
// measured ~5.7 TB/s). col4 loop-invariant; weights re-read per iter (L1-hot).
// ---------------------------------------------------------------------------
__global__ __launch_bounds__(256) void out_kernel(
    const float4* __restrict__ c4,
    const float4* __restrict__ w4,
    const float4* __restrict__ h4,
    const float4* __restrict__ wb4,
    float4* __restrict__ o4)
{
    const int total  = B_ * HW_ * (C_ / 4);
    const int stride = gridDim.x * blockDim.x;   // 2048*256, % 128 == 0
    const int col4   = (blockIdx.x * blockDim.x + threadIdx.x) & 127;

    for (int idx = blockIdx.x * blockDim.x + threadIdx.x; idx < total; idx += stride) {
        const int row = idx >> 7;
        const int b   = row / HW_;
        const float4* __restrict__ wb = wb4 + (long)b * (3 * C_ / 4);
        const float4 w0 = wb[col4];
        const float4 w1 = wb[128 + col4];
        const float4 w2 = wb[256 + col4];
        const float4 a = c4[idx];
        const float4 v = w4[idx];
        const float4 u = h4[idx];
        float4 o;
        o.x = a.x * w0.x + v.x * w1.x + u.x * w2.x;
        o.y = a.y * w0.y + v.y * w1.y + u.y * w2.y;
        o.z = a.z * w0.z + v.z * w1.z + u.z * w2.z;
        o.w = a.w * w0.w + v.w * w1.w + u.w * w2.w;
        o4[idx] = o;
    }
}

// ---------------------------------------------------------------------------
extern "C" void kernel_launch(void* const* d_in, const int* in_sizes, int n_in,
                              void* d_out, int out_size, void* d_ws, size_t ws_size,
                              hipStream_t stream)
{
    const float* c_e   = (const float*)d_in[0];
    const float* w_e   = (const float*)d_in[1];
    const float* h_e   = (const float*)d_in[2];
    const float* fc1_w = (const float*)d_in[3];
    const float* fc1_b = (const float*)d_in[4];
    const float* fc2_w = (const float*)d_in[5];
    const float* fc2_b = (const float*)d_in[6];
    float* out = (float*)d_out;

    // workspace: [partial: B*CH_*C][wbuf: B*3*C]  ~= 3.4 MB
    float* partial = (float*)d_ws;
    float* wbuf    = partial + (long)B_ * CH_ * C_;

    ps_kernel<<<dim3(CH_, B_), 256, 0, stream>>>(
        (const float4*)c_e, (const float4*)w_e, (const float4*)h_e,
        (float4*)partial);
    mlp_kernel<<<B_, 256, 0, stream>>>(partial, fc1_w, fc1_b, fc2_w, fc2_b, wbuf);
    out_kernel<<<2048, 256, 0, stream>>>(
        (const float4*)c_e, (const float4*)w_e, (const float4*)h_e,
        (const float4*)wbuf, (float4*)out);
}